// Round 5
// baseline (253.929 us; speedup 1.0000x reference)
//
#include <hip/hip_runtime.h>
#include <hip/hip_cooperative_groups.h>

namespace cg = cooperative_groups;

constexpr int kB = 256;
constexpr int kNC = 99;
constexpr int kN = 100;
constexpr int kC = 128;
constexpr int kH = 512;
constexpr int kL = 3;
constexpr int kNT = kB * kN;   // 25600
constexpr float kEps = 1e-5f;

typedef unsigned short u16;
typedef unsigned int u32;
typedef __attribute__((ext_vector_type(8))) __bf16 bf16x8;
typedef __attribute__((ext_vector_type(4))) float f32x4;

__device__ __forceinline__ u16 f2bf(float x) {
  union { float f; u32 u; } v; v.f = x;
  u32 r = (v.u + 0x7FFFu + ((v.u >> 16) & 1u)) >> 16;
  return (u16)r;
}

// per-channel BN affine from raw (sum, sumsq) stats; stats==nullptr -> identity
__device__ __forceinline__ void affine_from_stats(
    const float* __restrict__ stats, const float* __restrict__ gamma,
    const float* __restrict__ beta, int c, float& sc, float& sh) {
  if (stats != nullptr) {
    float s = stats[c], sq = stats[kC + c];
    float m = s * (1.0f / kNT);
    float v = sq * (1.0f / kNT) - m * m;
    float rs = rsqrtf(v + kEps);
    sc = gamma[c] * rs;
    sh = beta[c] - m * sc;
  } else {
    sc = 1.0f;
    sh = 0.0f;
  }
}

// ---- weight pack (432 blocks) + stats zero.
// pack layout: frag f; lane l; elem j: B[kb*32 + (l>>4)*8 + j][nb*16 + (l&15)]
//   gcn/W1: f = nb*4 + kb ; W2: f = nb*16 + kb
//   per layer: gcn frags [0,32), W1 [32,160), W2 [160,288), each frag 512 u16.
__global__ __launch_bounds__(256) void k_prep(
    const float* __restrict__ gcnW, const float* __restrict__ W1,
    const float* __restrict__ W2, u16* __restrict__ wpack,
    float* __restrict__ stats) {
  if (blockIdx.x == 0) {
    for (int i = threadIdx.x; i < kL * 2 * 2 * kC; i += 256) stats[i] = 0.0f;
  }
  int g = blockIdx.x * 256 + threadIdx.x;          // < 110592 float4-groups
  int layer = g / 36864, r = g % 36864;
  const float* src; int shf; u16* base; int isW2 = 0;
  if (r < 4096) {
    src = gcnW + (size_t)layer * kC * kC; shf = 7;
    base = wpack + (size_t)(layer * 288 + 0) * 512;
  } else if (r < 20480) {
    src = W1 + (size_t)layer * kC * kH; shf = 9;
    base = wpack + (size_t)(layer * 288 + 32) * 512; r -= 4096;
  } else {
    src = W2 + (size_t)layer * kH * kC; shf = 7;
    base = wpack + (size_t)(layer * 288 + 160) * 512; r -= 20480; isW2 = 1;
  }
  int e4 = r * 4;
  int k = e4 >> shf, n0 = e4 & ((1 << shf) - 1);
  float4 v = *(const float4*)(src + ((size_t)k << shf) + n0);
  float vv[4] = {v.x, v.y, v.z, v.w};
  int kb = k >> 5, hi = (k >> 3) & 3, j = k & 7;
#pragma unroll
  for (int t = 0; t < 4; ++t) {
    int n = n0 + t;
    int nb = n >> 4, l = hi * 16 + (n & 15);
    int f = isW2 ? (nb * 16 + kb) : (nb * 4 + kb);
    base[(size_t)f * 512 + l * 8 + j] = f2bf(vv[t]);
  }
}

// ---- persistent fused GNN: one block per graph, whole network in LDS.
// 256 blocks x 1024 threads, cooperative (grid.sync at BN stat boundaries).
__global__ __launch_bounds__(1024) void k_gnn(
    const float* __restrict__ dxy, const float* __restrict__ cxy,
    const float* __restrict__ dem, const float* __restrict__ Wd,
    const float* __restrict__ bd, const float* __restrict__ Wi,
    const float* __restrict__ bi, const u16* __restrict__ wpack,
    const float* __restrict__ gcn_b, const float* __restrict__ bn_gamma,
    const float* __restrict__ bn_beta, const float* __restrict__ ff_b1,
    const float* __restrict__ ff_b2, float* __restrict__ stats,
    float* __restrict__ out) {
  cg::grid_group grid = cg::this_grid();
  __shared__ __align__(16) float y[kN][kC];        // 51.2 KB f32 residual state
  __shared__ __align__(16) u16 xs[112][136];       // 30.5 KB bf16 A-tiles
  __shared__ __align__(16) float ubuf[16640];      // 66.6 KB: hs f32 [100]*132 | hid u16 [64]*520
  __shared__ float s_scale[kC], s_shift[kC], s_sum[kC], s_sq[kC];
  __shared__ float s_b1[kH], s_b2[kC];
  __shared__ float sP[8][kC];
  float* hs = ubuf;                 // stride 132
  u16* hid = (u16*)ubuf;            // stride 520

  const int tid = threadIdx.x;
  const int b = blockIdx.x;
  const int wave = tid >> 6, lane = tid & 63;
  const int arow = lane & 15, kofs = (lane >> 4) * 8;
  const int crow = (lane >> 4) * 4, ccol = lane & 15;
  const int jh = tid >> 7, cc = tid & 127;
  const int j0 = (jh < 4) ? jh * 13 : 52 + (jh - 4) * 12;
  const int jcnt = (jh < 4) ? 13 : 12;

  // initial embeddings into y
#pragma unroll
  for (int i = 0; i < 4; ++i) {
    int idx = i * 1024 + tid;
    if (idx < kN * 32) {
      int row = idx >> 5, c4 = (idx & 31) * 4;
      float4 o;
      if (row == 0) {
        float x0 = dxy[b * 2], x1 = dxy[b * 2 + 1];
        float4 w0 = *(const float4*)(Wd + c4);
        float4 w1 = *(const float4*)(Wd + kC + c4);
        float4 bb = *(const float4*)(bd + c4);
        o.x = fmaf(x0, w0.x, fmaf(x1, w1.x, bb.x));
        o.y = fmaf(x0, w0.y, fmaf(x1, w1.y, bb.y));
        o.z = fmaf(x0, w0.z, fmaf(x1, w1.z, bb.z));
        o.w = fmaf(x0, w0.w, fmaf(x1, w1.w, bb.w));
      } else {
        int q = b * kNC + (row - 1);
        float x0 = cxy[q * 2], x1 = cxy[q * 2 + 1], d = dem[q];
        float4 w0 = *(const float4*)(Wi + c4);
        float4 w1 = *(const float4*)(Wi + kC + c4);
        float4 w2 = *(const float4*)(Wi + 2 * kC + c4);
        float4 bb = *(const float4*)(bi + c4);
        o.x = fmaf(x0, w0.x, fmaf(x1, w1.x, fmaf(d, w2.x, bb.x)));
        o.y = fmaf(x0, w0.y, fmaf(x1, w1.y, fmaf(d, w2.y, bb.y)));
        o.z = fmaf(x0, w0.z, fmaf(x1, w1.z, fmaf(d, w2.z, bb.z)));
        o.w = fmaf(x0, w0.w, fmaf(x1, w1.w, fmaf(d, w2.w, bb.w)));
      }
      *(float4*)&y[row][c4] = o;
    }
  }

  // stage xs = bf16(affine(y)) rows 0..111 (zeros >= 100), using s_scale/s_shift
  auto stage_xs = [&]() {
#pragma unroll
    for (int i = 0; i < 4; ++i) {
      int idx = i * 1024 + tid;
      if (idx < 112 * 32) {
        int lr = idx >> 5, lc = (idx & 31) * 4;
        ushort4 h4 = {0, 0, 0, 0};
        if (lr < kN) {
          float4 g = *(const float4*)&y[lr][lc];
          h4.x = f2bf(fmaf(g.x, s_scale[lc + 0], s_shift[lc + 0]));
          h4.y = f2bf(fmaf(g.y, s_scale[lc + 1], s_shift[lc + 1]));
          h4.z = f2bf(fmaf(g.z, s_scale[lc + 2], s_shift[lc + 2]));
          h4.w = f2bf(fmaf(g.w, s_scale[lc + 3], s_shift[lc + 3]));
        }
        *(ushort4*)&xs[lr][lc] = h4;
      }
    }
  };

  for (int l = 0; l < kL; ++l) {
    const float* sp = l ? stats + ((l - 1) * 2 + 1) * 2 * kC : nullptr;
    const float* gp = l ? bn_gamma + (l - 1) * kC : nullptr;
    const float* bp = l ? bn_beta + (l - 1) * kC : nullptr;
    float* s0 = stats + (l * 2 + 0) * 2 * kC;
    float* s1 = stats + (l * 2 + 1) * 2 * kC;
    const u16* wg  = wpack + (size_t)(l * 288 + 0) * 512;
    const u16* w1p = wpack + (size_t)(l * 288 + 32) * 512;
    const u16* w2p = wpack + (size_t)(l * 288 + 160) * 512;

    // (1) pre-GCN affine params + zero stats accum
    if (tid < kC) {
      affine_from_stats(sp, gp, bp, tid, s_scale[tid], s_shift[tid]);
      s_sum[tid] = 0.0f;
      s_sq[tid] = 0.0f;
    }
    __syncthreads();
    // (2) stage xs
    stage_xs();
    __syncthreads();
    // (3) GCN MFMA -> hs. wave: nb = w>>1 (col block), th = w&1 (row half)
    {
      const int nb = wave >> 1, th = wave & 1;
      bf16x8 bfr[4];
#pragma unroll
      for (int kb = 0; kb < 4; ++kb)
        bfr[kb] = *(const bf16x8*)(wg + (size_t)(nb * 4 + kb) * 512 + lane * 8);
      const int t0 = th ? 4 : 0, t1 = th ? 7 : 4;
      for (int t = t0; t < t1; ++t) {
        f32x4 acc = {0.f, 0.f, 0.f, 0.f};
#pragma unroll
        for (int kb = 0; kb < 4; ++kb) {
          bf16x8 a = *(const bf16x8*)&xs[t * 16 + arow][kb * 32 + kofs];
          acc = __builtin_amdgcn_mfma_f32_16x16x32_bf16(a, bfr[kb], acc, 0, 0, 0);
        }
#pragma unroll
        for (int r = 0; r < 4; ++r) {
          int rr = t * 16 + crow + r;
          if (rr < kN) hs[rr * 132 + nb * 16 + ccol] = acc[r];
        }
      }
    }
    __syncthreads();
    // (4) prefix-agg + residual + bias -> y, local stats
    {
      const float gbc = gcn_b[l * kC + cc];
      float p = 0.0f;
      for (int jj = 0; jj < jcnt; ++jj) {
        int j = j0 + jj;
        p = fmaf(hs[j * 132 + cc], rsqrtf((float)(j + 1)), p);
      }
      sP[jh][cc] = p;
      __syncthreads();
      float s = 0.0f;
      for (int q = 0; q < jh; ++q) s += sP[q][cc];
      const float sc = s_scale[cc], sh = s_shift[cc];
      float lsum = 0.0f, lsq = 0.0f;
      for (int jj = 0; jj < jcnt; ++jj) {
        int j = j0 + jj;
        float r = rsqrtf((float)(j + 1));
        s = fmaf(hs[j * 132 + cc], r, s);
        float xv = fmaf(y[j][cc], sc, sh);
        float yv = xv + fmaf(s, r, gbc);
        y[j][cc] = yv;
        lsum += yv;
        lsq = fmaf(yv, yv, lsq);
      }
      atomicAdd(&s_sum[cc], lsum);
      atomicAdd(&s_sq[cc], lsq);
    }
    __syncthreads();
    // (5) push stats0, grid sync
    if (tid < kC) {
      atomicAdd(&s0[tid], s_sum[tid]);
      atomicAdd(&s0[kC + tid], s_sq[tid]);
    }
    grid.sync();
    // (6) FF affine params + biases + zero stats accum
    if (tid < kC) {
      affine_from_stats(s0, bn_gamma + l * kC, bn_beta + l * kC, tid,
                        s_scale[tid], s_shift[tid]);
      s_sum[tid] = 0.0f;
      s_sq[tid] = 0.0f;
      s_b2[tid] = ff_b2[l * kC + tid];
    }
    if (tid < kH) s_b1[tid] = ff_b1[l * kH + tid];
    __syncthreads();
    // (7) stage xs = bf16(affine0(y))
    stage_xs();
    __syncthreads();
    // (8) FF in 2 row-chunks (tiles 0..3 and 4..6), hid reuses ubuf
    for (int ch = 0; ch < 2; ++ch) {
      const int cbase = ch * 64;
      const int tcnt = ch ? 3 : 4;
      // FF1: hid = relu(xs @ W1 + b1); wave -> nb = {2w, 2w+1}
#pragma unroll
      for (int q = 0; q < 2; ++q) {
        const int nb = wave * 2 + q;
        bf16x8 bf[4];
#pragma unroll
        for (int kb = 0; kb < 4; ++kb)
          bf[kb] = *(const bf16x8*)(w1p + (size_t)(nb * 4 + kb) * 512 + lane * 8);
        const int c = nb * 16 + ccol;
        const float bbias = s_b1[c];
        for (int t = 0; t < tcnt; ++t) {
          f32x4 acc = {0.f, 0.f, 0.f, 0.f};
#pragma unroll
          for (int kb = 0; kb < 4; ++kb) {
            bf16x8 a = *(const bf16x8*)&xs[cbase + t * 16 + arow][kb * 32 + kofs];
            acc = __builtin_amdgcn_mfma_f32_16x16x32_bf16(a, bf[kb], acc, 0, 0, 0);
          }
#pragma unroll
          for (int r = 0; r < 4; ++r)
            hid[(t * 16 + crow + r) * 520 + c] = f2bf(fmaxf(acc[r] + bbias, 0.0f));
        }
      }
      __syncthreads();
      // FF2: y += hid @ W2 + b2 (+residual affine); wave -> nb = w&7, th = w>>3
      {
        const int nb = wave & 7, th = wave >> 3;
        const int c = nb * 16 + ccol;
        const float sc = s_scale[c], sh = s_shift[c], bb = s_b2[c];
        f32x4 acc[2] = {{0.f, 0.f, 0.f, 0.f}, {0.f, 0.f, 0.f, 0.f}};
#pragma unroll
        for (int half = 0; half < 2; ++half) {
          bf16x8 bw[8];
#pragma unroll
          for (int k8 = 0; k8 < 8; ++k8)
            bw[k8] = *(const bf16x8*)(w2p + (size_t)(nb * 16 + half * 8 + k8) * 512 + lane * 8);
#pragma unroll
          for (int tt = 0; tt < 2; ++tt) {
            const int tloc = th * 2 + tt;
            if (tloc < tcnt) {
#pragma unroll
              for (int k8 = 0; k8 < 8; ++k8) {
                bf16x8 ha = *(const bf16x8*)&hid[(tloc * 16 + arow) * 520 +
                                                 (half * 8 + k8) * 32 + kofs];
                acc[tt] = __builtin_amdgcn_mfma_f32_16x16x32_bf16(ha, bw[k8], acc[tt], 0, 0, 0);
              }
            }
          }
        }
        float ps = 0.0f, pq = 0.0f;
#pragma unroll
        for (int tt = 0; tt < 2; ++tt) {
          const int tloc = th * 2 + tt;
          if (tloc < tcnt) {
#pragma unroll
            for (int r = 0; r < 4; ++r) {
              int grow = cbase + tloc * 16 + crow + r;
              if (grow < kN) {
                float xv = fmaf(y[grow][c], sc, sh);
                float o = acc[tt][r] + bb + xv;
                y[grow][c] = o;
                ps += o;
                pq = fmaf(o, o, pq);
              }
            }
          }
        }
        atomicAdd(&s_sum[c], ps);
        atomicAdd(&s_sq[c], pq);
      }
      __syncthreads();
    }
    // (10) push stats1, grid sync
    if (tid < kC) {
      atomicAdd(&s1[tid], s_sum[tid]);
      atomicAdd(&s1[kC + tid], s_sq[tid]);
    }
    grid.sync();
  }

  // final BN apply + nodes + per-graph mean
  {
    const float* sf = stats + (2 * 2 + 1) * 2 * kC;
    if (tid < kC)
      affine_from_stats(sf, bn_gamma + 2 * kC, bn_beta + 2 * kC, tid,
                        s_scale[tid], s_shift[tid]);
    __syncthreads();
    const float sc = s_scale[cc], sh = s_shift[cc];
    float acc = 0.0f;
    for (int jj = 0; jj < jcnt; ++jj) {
      int j = j0 + jj;
      float xv = fmaf(y[j][cc], sc, sh);
      out[((size_t)b * kN + j) * kC + cc] = xv;
      acc += xv;
    }
    sP[jh][cc] = acc;
    __syncthreads();
    if (jh == 0) {
      float m = 0.0f;
#pragma unroll
      for (int q = 0; q < 8; ++q) m += sP[q][cc];
      out[(size_t)kNT * kC + (size_t)b * kC + cc] = m * (1.0f / kN);
    }
  }
}

extern "C" void kernel_launch(void* const* d_in, const int* in_sizes, int n_in,
                              void* d_out, int out_size, void* d_ws, size_t ws_size,
                              hipStream_t stream) {
  const float* depot_xy    = (const float*)d_in[0];
  const float* customer_xy = (const float*)d_in[1];
  const float* demand      = (const float*)d_in[2];
  const float* W_depot     = (const float*)d_in[3];
  const float* b_depot     = (const float*)d_in[4];
  const float* W_init      = (const float*)d_in[5];
  const float* b_init      = (const float*)d_in[6];
  const float* gcn_W       = (const float*)d_in[7];
  const float* gcn_b       = (const float*)d_in[8];
  const float* bn_gamma    = (const float*)d_in[9];
  const float* bn_beta     = (const float*)d_in[10];
  const float* ff_W1       = (const float*)d_in[11];
  const float* ff_b1       = (const float*)d_in[12];
  const float* ff_W2       = (const float*)d_in[13];
  const float* ff_b2       = (const float*)d_in[14];

  float* ws    = (float*)d_ws;
  float* stats = ws;                                    // 6 x (sum[128], sumsq[128])
  u16*   wpack = (u16*)(stats + kL * 2 * 2 * kC);
  float* outp  = (float*)d_out;

  k_prep<<<432, 256, 0, stream>>>(gcn_W, ff_W1, ff_W2, wpack, stats);

  void* args[] = {
      (void*)&depot_xy, (void*)&customer_xy, (void*)&demand,
      (void*)&W_depot, (void*)&b_depot, (void*)&W_init, (void*)&b_init,
      (void*)&wpack, (void*)&gcn_b, (void*)&bn_gamma, (void*)&bn_beta,
      (void*)&ff_b1, (void*)&ff_b2, (void*)&stats, (void*)&outp};
  hipLaunchCooperativeKernel((const void*)k_gnn, dim3(kB), dim3(1024), args, 0,
                             stream);
}

// Round 6
// 167.863 us; speedup vs baseline: 1.5127x; 1.5127x over previous
//
#include <hip/hip_runtime.h>

constexpr int kB = 256;
constexpr int kNC = 99;
constexpr int kN = 100;
constexpr int kC = 128;
constexpr int kH = 512;
constexpr int kL = 3;
constexpr int kNT = kB * kN;   // 25600
constexpr float kEps = 1e-5f;

typedef unsigned short u16;
typedef unsigned int u32;
typedef __attribute__((ext_vector_type(8))) __bf16 bf16x8;
typedef __attribute__((ext_vector_type(4))) float f32x4;

__device__ __forceinline__ u16 f2bf(float x) {
  union { float f; u32 u; } v; v.f = x;
  u32 r = (v.u + 0x7FFFu + ((v.u >> 16) & 1u)) >> 16;
  return (u16)r;
}

// per-channel BN affine from raw (sum, sumsq) stats; stats==nullptr -> identity
__device__ __forceinline__ void affine_from_stats(
    const float* __restrict__ stats, const float* __restrict__ gamma,
    const float* __restrict__ beta, int c, float& sc, float& sh) {
  if (stats != nullptr) {
    float s = stats[c], sq = stats[kC + c];
    float m = s * (1.0f / kNT);
    float v = sq * (1.0f / kNT) - m * m;
    float rs = rsqrtf(v + kEps);
    sc = gamma[c] * rs;
    sh = beta[c] - m * sc;
  } else {
    sc = 1.0f;
    sh = 0.0f;
  }
}

// ---- fused prep: weight pack (blocks 0..431) + initial embeddings (432..3631)
// pack layout: frag f; lane l; elem j: B[kb*32 + (l>>4)*8 + j][nb*16 + (l&15)]
//   gcn/W1: f = nb*4 + kb ; W2: f = nb*16 + kb
//   per layer: gcn frags [0,32), W1 [32,160), W2 [160,288), each frag 512 u16.
__global__ __launch_bounds__(256) void k_prep(
    const float* __restrict__ dxy, const float* __restrict__ cxy,
    const float* __restrict__ dem, const float* __restrict__ Wd,
    const float* __restrict__ bd, const float* __restrict__ Wi,
    const float* __restrict__ bi, const float* __restrict__ gcnW,
    const float* __restrict__ W1, const float* __restrict__ W2,
    float* __restrict__ yB, u16* __restrict__ wpack, float* __restrict__ stats) {
  if (blockIdx.x == 0) {
    for (int i = threadIdx.x; i < kL * 2 * 2 * kC; i += 256) stats[i] = 0.0f;
  }
  if (blockIdx.x < 432) {
    int g = blockIdx.x * 256 + threadIdx.x;          // < 110592 float4-groups
    int layer = g / 36864, r = g % 36864;
    const float* src; int shf; u16* base; int isW2 = 0;
    if (r < 4096) {
      src = gcnW + (size_t)layer * kC * kC; shf = 7;
      base = wpack + (size_t)(layer * 288 + 0) * 512;
    } else if (r < 20480) {
      src = W1 + (size_t)layer * kC * kH; shf = 9;
      base = wpack + (size_t)(layer * 288 + 32) * 512; r -= 4096;
    } else {
      src = W2 + (size_t)layer * kH * kC; shf = 7;
      base = wpack + (size_t)(layer * 288 + 160) * 512; r -= 20480; isW2 = 1;
    }
    int e4 = r * 4;
    int k = e4 >> shf, n0 = e4 & ((1 << shf) - 1);
    float4 v = *(const float4*)(src + ((size_t)k << shf) + n0);
    float vv[4] = {v.x, v.y, v.z, v.w};
    int kb = k >> 5, hi = (k >> 3) & 3, j = k & 7;
#pragma unroll
    for (int t = 0; t < 4; ++t) {
      int n = n0 + t;
      int nb = n >> 4, l = hi * 16 + (n & 15);
      int f = isW2 ? (nb * 16 + kb) : (nb * 4 + kb);
      base[(size_t)f * 512 + l * 8 + j] = f2bf(vv[t]);
    }
  } else {
    int g2 = (blockIdx.x - 432) * 256 + threadIdx.x;  // < 819200
    int row = g2 >> 5, c4 = (g2 & 31) * 4;
    int b = row / kN, j = row - b * kN;
    float4 o;
    if (j == 0) {
      float x0 = dxy[b * 2], x1 = dxy[b * 2 + 1];
      float4 w0 = *(const float4*)(Wd + c4);
      float4 w1 = *(const float4*)(Wd + kC + c4);
      float4 bb = *(const float4*)(bd + c4);
      o.x = fmaf(x0, w0.x, fmaf(x1, w1.x, bb.x));
      o.y = fmaf(x0, w0.y, fmaf(x1, w1.y, bb.y));
      o.z = fmaf(x0, w0.z, fmaf(x1, w1.z, bb.z));
      o.w = fmaf(x0, w0.w, fmaf(x1, w1.w, bb.w));
    } else {
      int q = b * kNC + (j - 1);
      float x0 = cxy[q * 2], x1 = cxy[q * 2 + 1], d = dem[q];
      float4 w0 = *(const float4*)(Wi + c4);
      float4 w1 = *(const float4*)(Wi + kC + c4);
      float4 w2 = *(const float4*)(Wi + 2 * kC + c4);
      float4 bb = *(const float4*)(bi + c4);
      o.x = fmaf(x0, w0.x, fmaf(x1, w1.x, fmaf(d, w2.x, bb.x)));
      o.y = fmaf(x0, w0.y, fmaf(x1, w1.y, fmaf(d, w2.y, bb.y)));
      o.z = fmaf(x0, w0.z, fmaf(x1, w1.z, fmaf(d, w2.z, bb.z)));
      o.w = fmaf(x0, w0.w, fmaf(x1, w1.w, fmaf(d, w2.w, bb.w)));
    }
    *(float4*)(yB + (size_t)row * kC + c4) = o;
  }
}

// ---- fused GCN layer, channel-split: 2 blocks per graph, 64 output channels
// each. h = affine(yprev)@W[:,half] (MFMA into LDS), then per-graph rsqrt-prefix
// + residual + gcn bias + BN stats for the owned channels. 256 thr = 4 waves.
__global__ __launch_bounds__(256) void k_gcn(
    const float* __restrict__ yprev, const float* __restrict__ stats_prev,
    const float* __restrict__ gamma_p, const float* __restrict__ beta_p,
    const u16* __restrict__ Wg, const float* __restrict__ gb,
    float* __restrict__ stats_out, float* __restrict__ yA) {
  __shared__ float s_scale[kC], s_shift[kC];
  __shared__ u16 xs[112][136];       // 30.5 KB, rows >=100 are dummy
  __shared__ float hs[kN][68];       // 27.2 KB (stride 68: 2-way on write)
  __shared__ float sP[4][64], s_sum[64], s_sq[64];
  const int tid = threadIdx.x;
  const int b = blockIdx.x >> 1, half = blockIdx.x & 1;
  if (tid < kC) affine_from_stats(stats_prev, gamma_p, beta_p, tid,
                                  s_scale[tid], s_shift[tid]);
  if (tid < 64) { s_sum[tid] = 0.0f; s_sq[tid] = 0.0f; }
  __syncthreads();
  const size_t gbase = (size_t)b * kN * kC;
  // stage x (BN-affined, bf16) into LDS: 112*32 = 3584 float4-groups
#pragma unroll
  for (int i = 0; i < 14; ++i) {
    int li = i * 256 + tid;
    int lr = li >> 5, lc = (li & 31) * 4;
    float4 g = {0.f, 0.f, 0.f, 0.f};
    if (lr < kN) g = *(const float4*)(yprev + gbase + (size_t)lr * kC + lc);
    ushort4 h4;
    h4.x = f2bf(fmaf(g.x, s_scale[lc + 0], s_shift[lc + 0]));
    h4.y = f2bf(fmaf(g.y, s_scale[lc + 1], s_shift[lc + 1]));
    h4.z = f2bf(fmaf(g.z, s_scale[lc + 2], s_shift[lc + 2]));
    h4.w = f2bf(fmaf(g.w, s_scale[lc + 3], s_shift[lc + 3]));
    *(ushort4*)&xs[lr][lc] = h4;
  }
  __syncthreads();
  const int wave = tid >> 6, lane = tid & 63;
  const int arow = lane & 15, kofs = (lane >> 4) * 8;
  const int crow = (lane >> 4) * 4, ccol = lane & 15;
  // wave w owns global col block nb = half*4+w; 4 B-frags in regs
  {
    const int nb = half * 4 + wave;
    bf16x8 bfr[4];
#pragma unroll
    for (int kb = 0; kb < 4; ++kb)
      bfr[kb] = *(const bf16x8*)(Wg + (size_t)(nb * 4 + kb) * 512 + lane * 8);
#pragma unroll
    for (int t = 0; t < 7; ++t) {
      f32x4 acc = {0.f, 0.f, 0.f, 0.f};
#pragma unroll
      for (int kb = 0; kb < 4; ++kb) {
        bf16x8 a = *(const bf16x8*)&xs[t * 16 + arow][kb * 32 + kofs];
        acc = __builtin_amdgcn_mfma_f32_16x16x32_bf16(a, bfr[kb], acc, 0, 0, 0);
      }
      int rbase = t * 16 + crow;
#pragma unroll
      for (int r = 0; r < 4; ++r)
        if (rbase + r < kN) hs[rbase + r][wave * 16 + ccol] = acc[r];
    }
  }
  __syncthreads();
  // prefix over j (4-way split) for owned 64 channels, residual, bias, stats
  const int c = tid & 63, jh = tid >> 6;
  const int ch = half * 64 + c;
  const float sc = s_scale[ch], sh = s_shift[ch];
  const float gbc = gb[ch];
  const int j0 = jh * 25;
  float p = 0.0f;
#pragma unroll
  for (int jj = 0; jj < 25; ++jj)
    p = fmaf(hs[j0 + jj][c], rsqrtf((float)(j0 + jj + 1)), p);
  sP[jh][c] = p;
  __syncthreads();
  float s = 0.0f;
  for (int q = 0; q < jh; ++q) s += sP[q][c];
  float lsum = 0.0f, lsq = 0.0f;
#pragma unroll
  for (int jj = 0; jj < 25; ++jj) {
    int j = j0 + jj;
    float r = rsqrtf((float)(j + 1));
    s = fmaf(hs[j][c], r, s);
    float xv = fmaf(yprev[gbase + (size_t)j * kC + ch], sc, sh);
    float yv = xv + fmaf(s, r, gbc);
    yA[gbase + (size_t)j * kC + ch] = yv;
    lsum += yv;
    lsq = fmaf(yv, yv, lsq);
  }
  atomicAdd(&s_sum[c], lsum);
  atomicAdd(&s_sq[c], lsq);
  __syncthreads();
  if (tid < 64) {
    atomicAdd(&stats_out[ch - c + tid], s_sum[tid]);
    atomicAdd(&stats_out[kC + ch - c + tid], s_sq[tid]);
  }
}

// fused FF (MFMA bf16): 32-row tile, 8 waves. phase1 N-split (64 cols/wave),
// phase2 N-split (16 cols/wave). hid transposed via LDS.
__global__ __launch_bounds__(512) void k_ff(
    const float* __restrict__ yA, const float* __restrict__ stats_in,
    const float* __restrict__ gamma, const float* __restrict__ beta,
    const u16* __restrict__ W1p, const float* __restrict__ b1,
    const u16* __restrict__ W2p, const float* __restrict__ b2,
    float* __restrict__ stats_out, float* __restrict__ yB) {
  __shared__ float s_scale[kC], s_shift[kC], s_sum[kC], s_sq[kC];
  __shared__ float s_b1[kH];
  __shared__ u16 xs[32][136];
  __shared__ u16 hid[32][520];
  const int tid = threadIdx.x;
  if (tid < kC) {
    affine_from_stats(stats_in, gamma, beta, tid, s_scale[tid], s_shift[tid]);
    s_sum[tid] = 0.0f;
    s_sq[tid] = 0.0f;
  }
  if (tid < 128) ((float4*)s_b1)[tid] = ((const float4*)b1)[tid];
  __syncthreads();
  const int rb = blockIdx.x * 32;
#pragma unroll
  for (int i = 0; i < 2; ++i) {
    int li = i * 2048 + tid * 4;
    int lr = li >> 7, lc = li & 127;
    float4 g = *(const float4*)(yA + (size_t)(rb + lr) * kC + lc);
    ushort4 h4;
    h4.x = f2bf(fmaf(g.x, s_scale[lc + 0], s_shift[lc + 0]));
    h4.y = f2bf(fmaf(g.y, s_scale[lc + 1], s_shift[lc + 1]));
    h4.z = f2bf(fmaf(g.z, s_scale[lc + 2], s_shift[lc + 2]));
    h4.w = f2bf(fmaf(g.w, s_scale[lc + 3], s_shift[lc + 3]));
    *(ushort4*)&xs[lr][lc] = h4;
  }
  __syncthreads();
  const int wave = tid >> 6, lane = tid & 63;
  const int arow = lane & 15, kofs = (lane >> 4) * 8;
  const int crow = (lane >> 4) * 4, ccol = lane & 15;
  bf16x8 a[2][4];
#pragma unroll
  for (int rb2 = 0; rb2 < 2; ++rb2)
#pragma unroll
    for (int kb = 0; kb < 4; ++kb)
      a[rb2][kb] = *(const bf16x8*)&xs[rb2 * 16 + arow][kb * 32 + kofs];

  // ---- phase 1: hid = relu(xs @ W1 + b1); wave handles nb = wave*4 .. wave*4+3
  const u16* w1f = W1p + lane * 8;
#pragma unroll
  for (int t = 0; t < 4; ++t) {
    const int nb = wave * 4 + t;
    f32x4 acc0 = {0.f, 0.f, 0.f, 0.f}, acc1 = {0.f, 0.f, 0.f, 0.f};
#pragma unroll
    for (int kb = 0; kb < 4; ++kb) {
      bf16x8 bfrag = *(const bf16x8*)(w1f + (size_t)(nb * 4 + kb) * 512);
      acc0 = __builtin_amdgcn_mfma_f32_16x16x32_bf16(a[0][kb], bfrag, acc0, 0, 0, 0);
      acc1 = __builtin_amdgcn_mfma_f32_16x16x32_bf16(a[1][kb], bfrag, acc1, 0, 0, 0);
    }
    const int c = nb * 16 + ccol;
    const float bbias = s_b1[c];
#pragma unroll
    for (int r = 0; r < 4; ++r) {
      hid[crow + r][c]      = f2bf(fmaxf(acc0[r] + bbias, 0.0f));
      hid[16 + crow + r][c] = f2bf(fmaxf(acc1[r] + bbias, 0.0f));
    }
  }
  __syncthreads();

  // ---- phase 2: out = x + hid @ W2 + b2; wave handles nb = wave
  const u16* w2f = W2p + lane * 8;
  f32x4 oacc0 = {0.f, 0.f, 0.f, 0.f}, oacc1 = {0.f, 0.f, 0.f, 0.f};
#pragma unroll
  for (int kb = 0; kb < 16; ++kb) {
    bf16x8 ha0 = *(const bf16x8*)&hid[arow][kb * 32 + kofs];
    bf16x8 ha1 = *(const bf16x8*)&hid[16 + arow][kb * 32 + kofs];
    bf16x8 bfrag = *(const bf16x8*)(w2f + (size_t)(wave * 16 + kb) * 512);
    oacc0 = __builtin_amdgcn_mfma_f32_16x16x32_bf16(ha0, bfrag, oacc0, 0, 0, 0);
    oacc1 = __builtin_amdgcn_mfma_f32_16x16x32_bf16(ha1, bfrag, oacc1, 0, 0, 0);
  }

  // ---- epilogue: bias + f32 residual, store, BN stats
  const int c = wave * 16 + ccol;
  const float sc = s_scale[c], sh = s_shift[c], bb = b2[c];
  float psum = 0.0f, psq = 0.0f;
#pragma unroll
  for (int rb2 = 0; rb2 < 2; ++rb2) {
#pragma unroll
    for (int r = 0; r < 4; ++r) {
      int row = rb + rb2 * 16 + crow + r;
      float xv = fmaf(yA[(size_t)row * kC + c], sc, sh);
      float o = (rb2 ? oacc1[r] : oacc0[r]) + bb + xv;
      yB[(size_t)row * kC + c] = o;
      psum += o;
      psq = fmaf(o, o, psq);
    }
  }
  atomicAdd(&s_sum[c], psum);
  atomicAdd(&s_sq[c], psq);
  __syncthreads();
  if (tid < kC) {
    atomicAdd(&stats_out[tid], s_sum[tid]);
    atomicAdd(&stats_out[kC + tid], s_sq[tid]);
  }
}

// final BN apply + nodes out + per-graph mean, 4-way j-split
__global__ __launch_bounds__(512) void k_out(
    const float* __restrict__ yB, const float* __restrict__ stats,
    const float* __restrict__ gamma, const float* __restrict__ beta,
    float* __restrict__ out) {
  __shared__ float sP[4][kC];
  const int b = blockIdx.x;
  const int c = threadIdx.x & 127, jh = threadIdx.x >> 7;
  float sc, sh;
  affine_from_stats(stats, gamma, beta, c, sc, sh);
  float acc = 0.0f;
  const size_t base = (size_t)b * kN * kC + c;
  const int j0 = jh * 25;
#pragma unroll
  for (int jj = 0; jj < 25; ++jj) {
    float xv = fmaf(yB[base + (size_t)(j0 + jj) * kC], sc, sh);
    out[base + (size_t)(j0 + jj) * kC] = xv;
    acc += xv;
  }
  sP[jh][c] = acc;
  __syncthreads();
  if (jh == 0)
    out[(size_t)kNT * kC + (size_t)b * kC + c] =
        (sP[0][c] + sP[1][c] + sP[2][c] + sP[3][c]) * (1.0f / kN);
}

extern "C" void kernel_launch(void* const* d_in, const int* in_sizes, int n_in,
                              void* d_out, int out_size, void* d_ws, size_t ws_size,
                              hipStream_t stream) {
  const float* depot_xy    = (const float*)d_in[0];
  const float* customer_xy = (const float*)d_in[1];
  const float* demand      = (const float*)d_in[2];
  const float* W_depot     = (const float*)d_in[3];
  const float* b_depot     = (const float*)d_in[4];
  const float* W_init      = (const float*)d_in[5];
  const float* b_init      = (const float*)d_in[6];
  const float* gcn_W       = (const float*)d_in[7];
  const float* gcn_b       = (const float*)d_in[8];
  const float* bn_gamma    = (const float*)d_in[9];
  const float* bn_beta     = (const float*)d_in[10];
  const float* ff_W1       = (const float*)d_in[11];
  const float* ff_b1       = (const float*)d_in[12];
  const float* ff_W2       = (const float*)d_in[13];
  const float* ff_b2       = (const float*)d_in[14];

  float* ws    = (float*)d_ws;
  float* yA    = ws;
  float* yB    = ws + (size_t)kNT * kC;
  float* stats = ws + 2 * (size_t)kNT * kC;   // 6 slots x (sum[128], sumsq[128])
  u16*   wpack = (u16*)(stats + kL * 2 * 2 * kC);

  k_prep<<<3632, 256, 0, stream>>>(depot_xy, customer_xy, demand, W_depot, b_depot,
                                   W_init, b_init, gcn_W, ff_W1, ff_W2,
                                   yB, wpack, stats);
  for (int l = 0; l < kL; ++l) {
    const float* sp = (l == 0) ? nullptr : stats + ((l - 1) * 2 + 1) * 2 * kC;
    const float* gp = (l == 0) ? nullptr : bn_gamma + (l - 1) * kC;
    const float* bp = (l == 0) ? nullptr : bn_beta + (l - 1) * kC;
    float* s0 = stats + (l * 2 + 0) * 2 * kC;
    float* s1 = stats + (l * 2 + 1) * 2 * kC;
    const u16* wg  = wpack + (size_t)(l * 288 + 0) * 512;
    const u16* w1p = wpack + (size_t)(l * 288 + 32) * 512;
    const u16* w2p = wpack + (size_t)(l * 288 + 160) * 512;
    k_gcn<<<kB * 2, 256, 0, stream>>>(yB, sp, gp, bp, wg, gcn_b + l * kC, s0, yA);
    k_ff<<<kNT / 32, 512, 0, stream>>>(yA, s0, bn_gamma + l * kC, bn_beta + l * kC,
                                       w1p, ff_b1 + l * kH,
                                       w2p, ff_b2 + l * kC,
                                       s1, yB);
  }
  k_out<<<kB, 512, 0, stream>>>(yB, stats + (2 * 2 + 1) * 2 * kC,
                                bn_gamma + 2 * kC, bn_beta + 2 * kC, (float*)d_out);
}

// Round 7
// 161.385 us; speedup vs baseline: 1.5734x; 1.0401x over previous
//
#include <hip/hip_runtime.h>

constexpr int kB = 256;
constexpr int kNC = 99;
constexpr int kN = 100;
constexpr int kC = 128;
constexpr int kH = 512;
constexpr int kL = 3;
constexpr int kNT = kB * kN;   // 25600
constexpr float kEps = 1e-5f;

typedef unsigned short u16;
typedef unsigned int u32;
typedef __attribute__((ext_vector_type(8))) __bf16 bf16x8;
typedef __attribute__((ext_vector_type(4))) float f32x4;

__device__ __forceinline__ u16 f2bf(float x) {
  __bf16 h = (__bf16)x;                 // native v_cvt (RNE), 1 VALU op
  return __builtin_bit_cast(u16, h);
}

// per-channel BN affine from raw (sum, sumsq) stats; stats==nullptr -> identity
__device__ __forceinline__ void affine_from_stats(
    const float* __restrict__ stats, const float* __restrict__ gamma,
    const float* __restrict__ beta, int c, float& sc, float& sh) {
  if (stats != nullptr) {
    float s = stats[c], sq = stats[kC + c];
    float m = s * (1.0f / kNT);
    float v = sq * (1.0f / kNT) - m * m;
    float rs = rsqrtf(v + kEps);
    sc = gamma[c] * rs;
    sh = beta[c] - m * sc;
  } else {
    sc = 1.0f;
    sh = 0.0f;
  }
}

// ---- weight pack (432 blocks) + stats zero.
// pack layout: frag f; lane l; elem j: B[kb*32 + (l>>4)*8 + j][nb*16 + (l&15)]
//   gcn/W1: f = nb*4 + kb ; W2: f = nb*16 + kb
//   per layer: gcn frags [0,32), W1 [32,160), W2 [160,288), each frag 512 u16.
__global__ __launch_bounds__(256) void k_prep(
    const float* __restrict__ gcnW, const float* __restrict__ W1,
    const float* __restrict__ W2, u16* __restrict__ wpack,
    float* __restrict__ stats) {
  if (blockIdx.x == 0) {
    for (int i = threadIdx.x; i < kL * 2 * 2 * kC; i += 256) stats[i] = 0.0f;
  }
  int g = blockIdx.x * 256 + threadIdx.x;          // < 110592 float4-groups
  int layer = g / 36864, r = g % 36864;
  const float* src; int shf; u16* base; int isW2 = 0;
  if (r < 4096) {
    src = gcnW + (size_t)layer * kC * kC; shf = 7;
    base = wpack + (size_t)(layer * 288 + 0) * 512;
  } else if (r < 20480) {
    src = W1 + (size_t)layer * kC * kH; shf = 9;
    base = wpack + (size_t)(layer * 288 + 32) * 512; r -= 4096;
  } else {
    src = W2 + (size_t)layer * kH * kC; shf = 7;
    base = wpack + (size_t)(layer * 288 + 160) * 512; r -= 20480; isW2 = 1;
  }
  int e4 = r * 4;
  int k = e4 >> shf, n0 = e4 & ((1 << shf) - 1);
  float4 v = *(const float4*)(src + ((size_t)k << shf) + n0);
  float vv[4] = {v.x, v.y, v.z, v.w};
  int kb = k >> 5, hi = (k >> 3) & 3, j = k & 7;
#pragma unroll
  for (int t = 0; t < 4; ++t) {
    int n = n0 + t;
    int nb = n >> 4, l = hi * 16 + (n & 15);
    int f = isW2 ? (nb * 16 + kb) : (nb * 4 + kb);
    base[(size_t)f * 512 + l * 8 + j] = f2bf(vv[t]);
  }
}

// ---- fused GCN layer, channel-split: 2 blocks per graph, 64 output channels
// each. FIRST=true computes initial embeddings from coords on the fly (no
// global activation input). h = affine(x)@W[:,half] (MFMA into LDS), then
// per-graph rsqrt-prefix + residual + gcn bias + BN stats. 256 thr = 4 waves.
template <bool FIRST>
__global__ __launch_bounds__(256) void k_gcn(
    const float* __restrict__ yprev, const float* __restrict__ stats_prev,
    const float* __restrict__ gamma_p, const float* __restrict__ beta_p,
    const u16* __restrict__ Wg, const float* __restrict__ gb,
    float* __restrict__ stats_out, float* __restrict__ yA,
    const float* __restrict__ dxy, const float* __restrict__ cxy,
    const float* __restrict__ dem, const float* __restrict__ Wd,
    const float* __restrict__ bd, const float* __restrict__ Wi,
    const float* __restrict__ bi) {
  __shared__ float s_scale[kC], s_shift[kC];
  __shared__ u16 xs[112][136];       // 30.5 KB, rows >=100 are dummy
  __shared__ float hs[kN][68];       // 27.2 KB
  __shared__ float sP[4][64], s_sum[64], s_sq[64];
  __shared__ float scoord[kN][4];    // FIRST only: (x, y, demand)
  __shared__ float swt[7][kC];       // FIRST only: Wd0,Wd1,bd,Wi0,Wi1,Wi2,bi
  const int tid = threadIdx.x;
  const int b = blockIdx.x >> 1, half = blockIdx.x & 1;
  if (FIRST) {
    if (tid < kN) {
      if (tid == 0) {
        scoord[0][0] = dxy[b * 2];
        scoord[0][1] = dxy[b * 2 + 1];
        scoord[0][2] = 0.0f;
      } else {
        int q = b * kNC + tid - 1;
        scoord[tid][0] = cxy[q * 2];
        scoord[tid][1] = cxy[q * 2 + 1];
        scoord[tid][2] = dem[q];
      }
    }
    if (tid < 224) {
      int f = tid * 4, r = f >> 7, c = f & 127;
      const float* s;
      switch (r) {
        case 0: s = Wd + c; break;
        case 1: s = Wd + kC + c; break;
        case 2: s = bd + c; break;
        case 3: s = Wi + c; break;
        case 4: s = Wi + kC + c; break;
        case 5: s = Wi + 2 * kC + c; break;
        default: s = bi + c; break;
      }
      *(float4*)&swt[r][c] = *(const float4*)s;
    }
  }
  if (tid < kC) affine_from_stats(stats_prev, gamma_p, beta_p, tid,
                                  s_scale[tid], s_shift[tid]);
  if (tid < 64) { s_sum[tid] = 0.0f; s_sq[tid] = 0.0f; }
  __syncthreads();
  const size_t gbase = (size_t)b * kN * kC;
  // stage x (BN-affined, bf16) into LDS: 112*32 = 3584 float4-groups
#pragma unroll
  for (int i = 0; i < 14; ++i) {
    int li = i * 256 + tid;
    int lr = li >> 5, lc = (li & 31) * 4;
    float4 g = {0.f, 0.f, 0.f, 0.f};
    if (lr < kN) {
      if (FIRST) {
        float sx = scoord[lr][0], sy = scoord[lr][1], sd = scoord[lr][2];
        if (lr == 0) {
#pragma unroll
          for (int t = 0; t < 4; ++t)
            (&g.x)[t] = fmaf(sx, swt[0][lc + t],
                             fmaf(sy, swt[1][lc + t], swt[2][lc + t]));
        } else {
#pragma unroll
          for (int t = 0; t < 4; ++t)
            (&g.x)[t] = fmaf(sx, swt[3][lc + t],
                             fmaf(sy, swt[4][lc + t],
                                  fmaf(sd, swt[5][lc + t], swt[6][lc + t])));
        }
      } else {
        g = *(const float4*)(yprev + gbase + (size_t)lr * kC + lc);
      }
    }
    ushort4 h4;
    h4.x = f2bf(fmaf(g.x, s_scale[lc + 0], s_shift[lc + 0]));
    h4.y = f2bf(fmaf(g.y, s_scale[lc + 1], s_shift[lc + 1]));
    h4.z = f2bf(fmaf(g.z, s_scale[lc + 2], s_shift[lc + 2]));
    h4.w = f2bf(fmaf(g.w, s_scale[lc + 3], s_shift[lc + 3]));
    *(ushort4*)&xs[lr][lc] = h4;
  }
  __syncthreads();
  const int wave = tid >> 6, lane = tid & 63;
  const int arow = lane & 15, kofs = (lane >> 4) * 8;
  const int crow = (lane >> 4) * 4, ccol = lane & 15;
  // wave w owns global col block nb = half*4+w; 4 B-frags in regs
  {
    const int nb = half * 4 + wave;
    bf16x8 bfr[4];
#pragma unroll
    for (int kb = 0; kb < 4; ++kb)
      bfr[kb] = *(const bf16x8*)(Wg + (size_t)(nb * 4 + kb) * 512 + lane * 8);
#pragma unroll
    for (int t = 0; t < 7; ++t) {
      f32x4 acc = {0.f, 0.f, 0.f, 0.f};
#pragma unroll
      for (int kb = 0; kb < 4; ++kb) {
        bf16x8 a = *(const bf16x8*)&xs[t * 16 + arow][kb * 32 + kofs];
        acc = __builtin_amdgcn_mfma_f32_16x16x32_bf16(a, bfr[kb], acc, 0, 0, 0);
      }
      int rbase = t * 16 + crow;
#pragma unroll
      for (int r = 0; r < 4; ++r)
        if (rbase + r < kN) hs[rbase + r][wave * 16 + ccol] = acc[r];
    }
  }
  __syncthreads();
  // prefix over j (4-way split) for owned 64 channels, residual, bias, stats
  const int c = tid & 63, jh = tid >> 6;
  const int ch = half * 64 + c;
  const float sc = s_scale[ch], sh = s_shift[ch];
  const float gbc = gb[ch];
  const int j0 = jh * 25;
  float p = 0.0f;
#pragma unroll
  for (int jj = 0; jj < 25; ++jj)
    p = fmaf(hs[j0 + jj][c], rsqrtf((float)(j0 + jj + 1)), p);
  sP[jh][c] = p;
  __syncthreads();
  float s = 0.0f;
  for (int q = 0; q < jh; ++q) s += sP[q][c];
  // FIRST: residual x recomputed exactly (same fmaf order as staging)
  float wv0 = 0.f, wv1 = 0.f, wv2 = 0.f, wv3 = 0.f, wd0 = 0.f, wd1 = 0.f, wd2 = 0.f;
  if (FIRST) {
    wv0 = swt[3][ch]; wv1 = swt[4][ch]; wv2 = swt[5][ch]; wv3 = swt[6][ch];
    wd0 = swt[0][ch]; wd1 = swt[1][ch]; wd2 = swt[2][ch];
  }
  float lsum = 0.0f, lsq = 0.0f;
#pragma unroll
  for (int jj = 0; jj < 25; ++jj) {
    int j = j0 + jj;
    float r = rsqrtf((float)(j + 1));
    s = fmaf(hs[j][c], r, s);
    float xv;
    if (FIRST) {
      float sx = scoord[j][0], sy = scoord[j][1], sd = scoord[j][2];
      xv = (j == 0) ? fmaf(sx, wd0, fmaf(sy, wd1, wd2))
                    : fmaf(sx, wv0, fmaf(sy, wv1, fmaf(sd, wv2, wv3)));
    } else {
      xv = fmaf(yprev[gbase + (size_t)j * kC + ch], sc, sh);
    }
    float yv = xv + fmaf(s, r, gbc);
    yA[gbase + (size_t)j * kC + ch] = yv;
    lsum += yv;
    lsq = fmaf(yv, yv, lsq);
  }
  atomicAdd(&s_sum[c], lsum);
  atomicAdd(&s_sq[c], lsq);
  __syncthreads();
  if (tid < 64) {
    atomicAdd(&stats_out[half * 64 + tid], s_sum[tid]);
    atomicAdd(&stats_out[kC + half * 64 + tid], s_sq[tid]);
  }
}

// fused FF (MFMA bf16): 32-row tile, 8 waves. phase1 N-split (64 cols/wave),
// phase2 N-split (16 cols/wave). hid transposed via LDS.
__global__ __launch_bounds__(512) void k_ff(
    const float* __restrict__ yA, const float* __restrict__ stats_in,
    const float* __restrict__ gamma, const float* __restrict__ beta,
    const u16* __restrict__ W1p, const float* __restrict__ b1,
    const u16* __restrict__ W2p, const float* __restrict__ b2,
    float* __restrict__ stats_out, float* __restrict__ yB) {
  __shared__ float s_scale[kC], s_shift[kC], s_sum[kC], s_sq[kC];
  __shared__ float s_b1[kH];
  __shared__ u16 xs[32][136];
  __shared__ u16 hid[32][520];
  const int tid = threadIdx.x;
  if (tid < kC) {
    affine_from_stats(stats_in, gamma, beta, tid, s_scale[tid], s_shift[tid]);
    s_sum[tid] = 0.0f;
    s_sq[tid] = 0.0f;
  }
  if (tid < 128) ((float4*)s_b1)[tid] = ((const float4*)b1)[tid];
  __syncthreads();
  const int rb = blockIdx.x * 32;
#pragma unroll
  for (int i = 0; i < 2; ++i) {
    int li = i * 2048 + tid * 4;
    int lr = li >> 7, lc = li & 127;
    float4 g = *(const float4*)(yA + (size_t)(rb + lr) * kC + lc);
    ushort4 h4;
    h4.x = f2bf(fmaf(g.x, s_scale[lc + 0], s_shift[lc + 0]));
    h4.y = f2bf(fmaf(g.y, s_scale[lc + 1], s_shift[lc + 1]));
    h4.z = f2bf(fmaf(g.z, s_scale[lc + 2], s_shift[lc + 2]));
    h4.w = f2bf(fmaf(g.w, s_scale[lc + 3], s_shift[lc + 3]));
    *(ushort4*)&xs[lr][lc] = h4;
  }
  __syncthreads();
  const int wave = tid >> 6, lane = tid & 63;
  const int arow = lane & 15, kofs = (lane >> 4) * 8;
  const int crow = (lane >> 4) * 4, ccol = lane & 15;
  bf16x8 a[2][4];
#pragma unroll
  for (int rb2 = 0; rb2 < 2; ++rb2)
#pragma unroll
    for (int kb = 0; kb < 4; ++kb)
      a[rb2][kb] = *(const bf16x8*)&xs[rb2 * 16 + arow][kb * 32 + kofs];

  // ---- phase 1: hid = relu(xs @ W1 + b1); wave handles nb = wave*4 .. wave*4+3
  const u16* w1f = W1p + lane * 8;
#pragma unroll
  for (int t = 0; t < 4; ++t) {
    const int nb = wave * 4 + t;
    bf16x8 bfrag[4];
#pragma unroll
    for (int kb = 0; kb < 4; ++kb)
      bfrag[kb] = *(const bf16x8*)(w1f + (size_t)(nb * 4 + kb) * 512);
    f32x4 acc0 = {0.f, 0.f, 0.f, 0.f}, acc1 = {0.f, 0.f, 0.f, 0.f};
#pragma unroll
    for (int kb = 0; kb < 4; ++kb) {
      acc0 = __builtin_amdgcn_mfma_f32_16x16x32_bf16(a[0][kb], bfrag[kb], acc0, 0, 0, 0);
      acc1 = __builtin_amdgcn_mfma_f32_16x16x32_bf16(a[1][kb], bfrag[kb], acc1, 0, 0, 0);
    }
    const int c = nb * 16 + ccol;
    const float bbias = s_b1[c];
#pragma unroll
    for (int r = 0; r < 4; ++r) {
      hid[crow + r][c]      = f2bf(fmaxf(acc0[r] + bbias, 0.0f));
      hid[16 + crow + r][c] = f2bf(fmaxf(acc1[r] + bbias, 0.0f));
    }
  }
  __syncthreads();

  // ---- phase 2: out = x + hid @ W2 + b2; wave handles nb = wave
  const u16* w2f = W2p + lane * 8;
  f32x4 oacc0 = {0.f, 0.f, 0.f, 0.f}, oacc1 = {0.f, 0.f, 0.f, 0.f};
#pragma unroll
  for (int kb = 0; kb < 16; ++kb) {
    bf16x8 bfrag = *(const bf16x8*)(w2f + (size_t)(wave * 16 + kb) * 512);
    bf16x8 ha0 = *(const bf16x8*)&hid[arow][kb * 32 + kofs];
    bf16x8 ha1 = *(const bf16x8*)&hid[16 + arow][kb * 32 + kofs];
    oacc0 = __builtin_amdgcn_mfma_f32_16x16x32_bf16(ha0, bfrag, oacc0, 0, 0, 0);
    oacc1 = __builtin_amdgcn_mfma_f32_16x16x32_bf16(ha1, bfrag, oacc1, 0, 0, 0);
  }

  // ---- epilogue: bias + f32 residual, store, BN stats
  const int c = wave * 16 + ccol;
  const float sc = s_scale[c], sh = s_shift[c], bb = b2[c];
  float psum = 0.0f, psq = 0.0f;
#pragma unroll
  for (int rb2 = 0; rb2 < 2; ++rb2) {
#pragma unroll
    for (int r = 0; r < 4; ++r) {
      int row = rb + rb2 * 16 + crow + r;
      float xv = fmaf(yA[(size_t)row * kC + c], sc, sh);
      float o = (rb2 ? oacc1[r] : oacc0[r]) + bb + xv;
      yB[(size_t)row * kC + c] = o;
      psum += o;
      psq = fmaf(o, o, psq);
    }
  }
  atomicAdd(&s_sum[c], psum);
  atomicAdd(&s_sq[c], psq);
  __syncthreads();
  if (tid < kC) {
    atomicAdd(&stats_out[tid], s_sum[tid]);
    atomicAdd(&stats_out[kC + tid], s_sq[tid]);
  }
}

// final BN apply + nodes out + per-graph mean, 4-way j-split
__global__ __launch_bounds__(512) void k_out(
    const float* __restrict__ yB, const float* __restrict__ stats,
    const float* __restrict__ gamma, const float* __restrict__ beta,
    float* __restrict__ out) {
  __shared__ float sP[4][kC];
  const int b = blockIdx.x;
  const int c = threadIdx.x & 127, jh = threadIdx.x >> 7;
  float sc, sh;
  affine_from_stats(stats, gamma, beta, c, sc, sh);
  float acc = 0.0f;
  const size_t base = (size_t)b * kN * kC + c;
  const int j0 = jh * 25;
#pragma unroll
  for (int jj = 0; jj < 25; ++jj) {
    float xv = fmaf(yB[base + (size_t)(j0 + jj) * kC], sc, sh);
    out[base + (size_t)(j0 + jj) * kC] = xv;
    acc += xv;
  }
  sP[jh][c] = acc;
  __syncthreads();
  if (jh == 0)
    out[(size_t)kNT * kC + (size_t)b * kC + c] =
        (sP[0][c] + sP[1][c] + sP[2][c] + sP[3][c]) * (1.0f / kN);
}

extern "C" void kernel_launch(void* const* d_in, const int* in_sizes, int n_in,
                              void* d_out, int out_size, void* d_ws, size_t ws_size,
                              hipStream_t stream) {
  const float* depot_xy    = (const float*)d_in[0];
  const float* customer_xy = (const float*)d_in[1];
  const float* demand      = (const float*)d_in[2];
  const float* W_depot     = (const float*)d_in[3];
  const float* b_depot     = (const float*)d_in[4];
  const float* W_init      = (const float*)d_in[5];
  const float* b_init      = (const float*)d_in[6];
  const float* gcn_W       = (const float*)d_in[7];
  const float* gcn_b       = (const float*)d_in[8];
  const float* bn_gamma    = (const float*)d_in[9];
  const float* bn_beta     = (const float*)d_in[10];
  const float* ff_W1       = (const float*)d_in[11];
  const float* ff_b1       = (const float*)d_in[12];
  const float* ff_W2       = (const float*)d_in[13];
  const float* ff_b2       = (const float*)d_in[14];

  float* ws    = (float*)d_ws;
  float* yA    = ws;
  float* yB    = ws + (size_t)kNT * kC;
  float* stats = ws + 2 * (size_t)kNT * kC;   // 6 slots x (sum[128], sumsq[128])
  u16*   wpack = (u16*)(stats + kL * 2 * 2 * kC);

  k_prep<<<432, 256, 0, stream>>>(gcn_W, ff_W1, ff_W2, wpack, stats);
  for (int l = 0; l < kL; ++l) {
    const float* sp = (l == 0) ? nullptr : stats + ((l - 1) * 2 + 1) * 2 * kC;
    const float* gp = (l == 0) ? nullptr : bn_gamma + (l - 1) * kC;
    const float* bp = (l == 0) ? nullptr : bn_beta + (l - 1) * kC;
    float* s0 = stats + (l * 2 + 0) * 2 * kC;
    float* s1 = stats + (l * 2 + 1) * 2 * kC;
    const u16* wg  = wpack + (size_t)(l * 288 + 0) * 512;
    const u16* w1p = wpack + (size_t)(l * 288 + 32) * 512;
    const u16* w2p = wpack + (size_t)(l * 288 + 160) * 512;
    if (l == 0) {
      k_gcn<true><<<kB * 2, 256, 0, stream>>>(
          nullptr, sp, gp, bp, wg, gcn_b + l * kC, s0, yA,
          depot_xy, customer_xy, demand, W_depot, b_depot, W_init, b_init);
    } else {
      k_gcn<false><<<kB * 2, 256, 0, stream>>>(
          yB, sp, gp, bp, wg, gcn_b + l * kC, s0, yA,
          nullptr, nullptr, nullptr, nullptr, nullptr, nullptr, nullptr);
    }
    k_ff<<<kNT / 32, 512, 0, stream>>>(yA, s0, bn_gamma + l * kC, bn_beta + l * kC,
                                       w1p, ff_b1 + l * kH,
                                       w2p, ff_b2 + l * kC,
                                       s1, yB);
  }
  k_out<<<kB, 512, 0, stream>>>(yB, stats + (2 * 2 + 1) * 2 * kC,
                                bn_gamma + 2 * kC, bn_beta + 2 * kC, (float*)d_out);
}